// Round 1
// baseline (1092.102 us; speedup 1.0000x reference)
//
#include <hip/hip_runtime.h>
#include <hip/hip_bf16.h>
#include <math.h>

// Problem constants
#define Bv   4
#define LQv  1024
#define Cv   256
#define Hv   8
#define Lv   4
#define Pv   4
#define DFFv 1024
#define DHv  32
#define LSRCv 21760   // 128*128 + 64*64 + 32*32 + 16*16

// ---------------------------------------------------------------------------
// elementwise add: out = a + b   (float4 vectorized)
__global__ __launch_bounds__(256) void add_kernel(const float* __restrict__ a,
                                                  const float* __restrict__ b,
                                                  float* __restrict__ out, int n4) {
    int i = blockIdx.x * blockDim.x + threadIdx.x;
    if (i < n4) {
        float4 av = ((const float4*)a)[i];
        float4 bv = ((const float4*)b)[i];
        float4 o;
        o.x = av.x + bv.x; o.y = av.y + bv.y; o.z = av.z + bv.z; o.w = av.w + bv.w;
        ((float4*)out)[i] = o;
    }
}

// ---------------------------------------------------------------------------
// C[M,N] = A[M,K] @ W[N,K]^T + bias[N], optional relu.
// Requires M%64==0, N%64==0, K%16==0 (true for all our shapes).
#define BM 64
#define BN 64
#define BKt 16
__global__ __launch_bounds__(256) void gemm_bias(const float* __restrict__ A,
                                                 const float* __restrict__ W,
                                                 const float* __restrict__ bias,
                                                 float* __restrict__ Cmat,
                                                 int M, int N, int K, int relu) {
    __shared__ float As[BKt][BM];
    __shared__ float Bs[BKt][BN];
    const int bm = blockIdx.y * BM;
    const int bn = blockIdx.x * BN;
    const int tid = threadIdx.x;
    const int tr = (tid >> 4) << 2;   // row offset 0..60
    const int tc = (tid & 15) << 2;   // col offset 0..60
    float acc[4][4] = {};

    const int lrow = tid >> 2;          // 0..63
    const int lc4  = (tid & 3) << 2;    // 0,4,8,12
    const float* Aptr = A + (size_t)(bm + lrow) * K + lc4;
    const float* Wptr = W + (size_t)(bn + lrow) * K + lc4;

    for (int k0 = 0; k0 < K; k0 += BKt) {
        float4 a4 = *(const float4*)(Aptr + k0);
        float4 w4 = *(const float4*)(Wptr + k0);
        As[lc4 + 0][lrow] = a4.x; As[lc4 + 1][lrow] = a4.y;
        As[lc4 + 2][lrow] = a4.z; As[lc4 + 3][lrow] = a4.w;
        Bs[lc4 + 0][lrow] = w4.x; Bs[lc4 + 1][lrow] = w4.y;
        Bs[lc4 + 2][lrow] = w4.z; Bs[lc4 + 3][lrow] = w4.w;
        __syncthreads();
#pragma unroll
        for (int kk = 0; kk < BKt; ++kk) {
            float a0 = As[kk][tr + 0], a1 = As[kk][tr + 1];
            float a2 = As[kk][tr + 2], a3 = As[kk][tr + 3];
            float b0 = Bs[kk][tc + 0], b1 = Bs[kk][tc + 1];
            float b2 = Bs[kk][tc + 2], b3 = Bs[kk][tc + 3];
            acc[0][0] = fmaf(a0, b0, acc[0][0]); acc[0][1] = fmaf(a0, b1, acc[0][1]);
            acc[0][2] = fmaf(a0, b2, acc[0][2]); acc[0][3] = fmaf(a0, b3, acc[0][3]);
            acc[1][0] = fmaf(a1, b0, acc[1][0]); acc[1][1] = fmaf(a1, b1, acc[1][1]);
            acc[1][2] = fmaf(a1, b2, acc[1][2]); acc[1][3] = fmaf(a1, b3, acc[1][3]);
            acc[2][0] = fmaf(a2, b0, acc[2][0]); acc[2][1] = fmaf(a2, b1, acc[2][1]);
            acc[2][2] = fmaf(a2, b2, acc[2][2]); acc[2][3] = fmaf(a2, b3, acc[2][3]);
            acc[3][0] = fmaf(a3, b0, acc[3][0]); acc[3][1] = fmaf(a3, b1, acc[3][1]);
            acc[3][2] = fmaf(a3, b2, acc[3][2]); acc[3][3] = fmaf(a3, b3, acc[3][3]);
        }
        __syncthreads();
    }
#pragma unroll
    for (int i = 0; i < 4; ++i) {
#pragma unroll
        for (int j = 0; j < 4; ++j) {
            float v = acc[i][j] + bias[bn + tc + j];
            if (relu) v = fmaxf(v, 0.f);
            Cmat[(size_t)(bm + tr + i) * N + bn + tc + j] = v;
        }
    }
}

// ---------------------------------------------------------------------------
// Flash-style self-attention. One thread = one query row (of one head).
// grid: (LQ/64, H, B), block: 64
__global__ __launch_bounds__(64) void attn_kernel(const float* __restrict__ Q,
                                                  const float* __restrict__ Kb,
                                                  const float* __restrict__ Vb,
                                                  float* __restrict__ O) {
    const int b = blockIdx.z, h = blockIdx.y, qt = blockIdx.x;
    const int tid = threadIdx.x;
    const int q = qt * 64 + tid;
    __shared__ float Ks[64][32];
    __shared__ float Vs[64][32];

    float qreg[32];
    const float* qrow = Q + ((size_t)(b * LQv + q)) * Cv + h * DHv;
#pragma unroll
    for (int d = 0; d < 32; ++d) qreg[d] = qrow[d];

    float mval = -1e30f, lsum = 0.f;
    float acc[32] = {};
    const float scale = 0.17677669529663687f;  // 1/sqrt(32)

    for (int kt = 0; kt < LQv / 64; ++kt) {
        __syncthreads();
        for (int i = tid; i < 512; i += 64) {   // 64 keys * 8 float4
            int key = i >> 3, f4 = (i & 7) << 2;
            size_t base = ((size_t)(b * LQv + kt * 64 + key)) * Cv + h * DHv + f4;
            *(float4*)&Ks[key][f4] = *(const float4*)(Kb + base);
            *(float4*)&Vs[key][f4] = *(const float4*)(Vb + base);
        }
        __syncthreads();
#pragma unroll 1
        for (int ck = 0; ck < 4; ++ck) {
            float s[16];
            float cmax = mval;
#pragma unroll
            for (int j = 0; j < 16; ++j) {
                float dot = 0.f;
#pragma unroll
                for (int d = 0; d < 32; ++d) dot = fmaf(qreg[d], Ks[ck * 16 + j][d], dot);
                s[j] = dot * scale;
                cmax = fmaxf(cmax, s[j]);
            }
            float corr = __expf(mval - cmax);
            mval = cmax;
            lsum *= corr;
#pragma unroll
            for (int d = 0; d < 32; ++d) acc[d] *= corr;
#pragma unroll
            for (int j = 0; j < 16; ++j) {
                float p = __expf(s[j] - cmax);
                lsum += p;
#pragma unroll
                for (int d = 0; d < 32; ++d) acc[d] = fmaf(p, Vs[ck * 16 + j][d], acc[d]);
            }
        }
    }
    float inv = 1.f / lsum;
    float* orow = O + ((size_t)(b * LQv + q)) * Cv + h * DHv;
#pragma unroll
    for (int d = 0; d < 32; ++d) orow[d] = acc[d] * inv;
}

// ---------------------------------------------------------------------------
// Deformable sampling. grid: B*LQ blocks, 256 threads: thread = (h, d).
__global__ __launch_bounds__(256) void deform_sample(const float* __restrict__ value,
                                                     const float* __restrict__ offs,
                                                     const float* __restrict__ awl,
                                                     const float* __restrict__ ref,
                                                     float* __restrict__ out) {
    const int bq = blockIdx.x;          // b*LQ + q
    const int b = bq >> 10;
    const int tid = threadIdx.x;
    const int h = tid >> 5, d = tid & 31;

    // softmax over the 16 (l,p) attention-weight logits of this head
    const float* aw = awl + (size_t)bq * (Hv * Lv * Pv) + h * 16;
    float w[16];
    float mx = -1e30f;
#pragma unroll
    for (int j = 0; j < 16; ++j) { w[j] = aw[j]; mx = fmaxf(mx, w[j]); }
    float ssum = 0.f;
#pragma unroll
    for (int j = 0; j < 16; ++j) { w[j] = __expf(w[j] - mx); ssum += w[j]; }
    float invs = 1.f / ssum;

    const float* op = offs + (size_t)bq * 256 + h * 32;   // (L,P,2) for this head
    const float* rp = ref + (size_t)bq * (Lv * 2);

    const int starts[4] = {0, 16384, 20480, 21504};
    const int WHl[4] = {128, 64, 32, 16};

    float acc = 0.f;
#pragma unroll 1
    for (int l = 0; l < 4; ++l) {
        const int wl = WHl[l];
        const float rx = rp[l * 2 + 0], ry = rp[l * 2 + 1];
        const float* vbase = value + ((size_t)b * LSRCv + starts[l]) * Cv + h * DHv + d;
#pragma unroll 1
        for (int p = 0; p < 4; ++p) {
            float ox = op[l * 8 + p * 2 + 0], oy = op[l * 8 + p * 2 + 1];
            // (ref + off/norm)*wl - 0.5 == ref*wl + off - 0.5  (square levels)
            float x = rx * (float)wl + ox - 0.5f;
            float y = ry * (float)wl + oy - 0.5f;
            float fx0 = floorf(x), fy0 = floorf(y);
            int x0 = (int)fx0, y0 = (int)fy0;
            float tx = x - fx0, ty = y - fy0;
            float w00 = (1.f - tx) * (1.f - ty);
            float w10 = tx * (1.f - ty);
            float w01 = (1.f - tx) * ty;
            float w11 = tx * ty;
            float s = 0.f;
            bool xin0 = (x0 >= 0) & (x0 < wl);
            bool xin1 = (x0 + 1 >= 0) & (x0 + 1 < wl);
            bool yin0 = (y0 >= 0) & (y0 < wl);
            bool yin1 = (y0 + 1 >= 0) & (y0 + 1 < wl);
            if (yin0) {
                if (xin0) s = fmaf(w00, vbase[(size_t)(y0 * wl + x0) * Cv], s);
                if (xin1) s = fmaf(w10, vbase[(size_t)(y0 * wl + x0 + 1) * Cv], s);
            }
            if (yin1) {
                if (xin0) s = fmaf(w01, vbase[(size_t)((y0 + 1) * wl + x0) * Cv], s);
                if (xin1) s = fmaf(w11, vbase[(size_t)((y0 + 1) * wl + x0 + 1) * Cv], s);
            }
            acc = fmaf(w[l * 4 + p] * invs, s, acc);
        }
    }
    out[(size_t)bq * Cv + h * DHv + d] = acc;
}

// ---------------------------------------------------------------------------
// out = LayerNorm(x + r) * g + b    one block per row of 256
__global__ __launch_bounds__(256) void ln_residual(const float* __restrict__ x,
                                                   const float* __restrict__ r,
                                                   const float* __restrict__ g,
                                                   const float* __restrict__ bta,
                                                   float* __restrict__ out) {
    const int row = blockIdx.x;
    const int tid = threadIdx.x;
    float v = x[(size_t)row * Cv + tid] + r[(size_t)row * Cv + tid];
    float s = v, sq = v * v;
#pragma unroll
    for (int off = 32; off > 0; off >>= 1) {
        s  += __shfl_down(s, off, 64);
        sq += __shfl_down(sq, off, 64);
    }
    __shared__ float ss[4], sqq[4];
    int wid = tid >> 6;
    if ((tid & 63) == 0) { ss[wid] = s; sqq[wid] = sq; }
    __syncthreads();
    __shared__ float meansh, rstdsh;
    if (tid == 0) {
        float S = ss[0] + ss[1] + ss[2] + ss[3];
        float Q = sqq[0] + sqq[1] + sqq[2] + sqq[3];
        float mean = S * (1.f / Cv);
        float var = Q * (1.f / Cv) - mean * mean;
        meansh = mean;
        rstdsh = rsqrtf(var + 1e-5f);
    }
    __syncthreads();
    out[(size_t)row * Cv + tid] = (v - meansh) * rstdsh * g[tid] + bta[tid];
}

// ---------------------------------------------------------------------------
extern "C" void kernel_launch(void* const* d_in, const int* in_sizes, int n_in,
                              void* d_out, int out_size, void* d_ws, size_t ws_size,
                              hipStream_t stream) {
    const float* tgt       = (const float*)d_in[0];
    const float* query_pos = (const float*)d_in[1];
    const float* ref_pts   = (const float*)d_in[2];
    const float* src       = (const float*)d_in[3];
    const float* in_w      = (const float*)d_in[4];
    const float* in_b      = (const float*)d_in[5];
    const float* sa_w      = (const float*)d_in[6];
    const float* sa_b      = (const float*)d_in[7];
    const float* off_w     = (const float*)d_in[8];
    const float* off_b     = (const float*)d_in[9];
    const float* aw_w      = (const float*)d_in[10];
    const float* aw_b      = (const float*)d_in[11];
    const float* val_w     = (const float*)d_in[12];
    const float* val_b     = (const float*)d_in[13];
    const float* co_w      = (const float*)d_in[14];
    const float* co_b      = (const float*)d_in[15];
    const float* ln1_g     = (const float*)d_in[16];
    const float* ln1_b     = (const float*)d_in[17];
    const float* ln2_g     = (const float*)d_in[18];
    const float* ln2_b     = (const float*)d_in[19];
    const float* ln3_g     = (const float*)d_in[20];
    const float* ln3_b     = (const float*)d_in[21];
    const float* f1_w      = (const float*)d_in[22];
    const float* f1_b      = (const float*)d_in[23];
    const float* f2_w      = (const float*)d_in[24];
    const float* f2_b      = (const float*)d_in[25];

    const int M0  = Bv * LQv * Cv;          // 1048576
    const int VSZ = Bv * LSRCv * Cv;        // 22282240
    float* ws = (float*)d_ws;

    // Phase-A buffers alias the (later) value region — lifetimes don't overlap.
    float* big    = ws;                     // VSZ floats
    float* qk     = big;
    float* qb     = big + (size_t)M0;
    float* kb     = big + (size_t)2 * M0;
    float* vb     = big + (size_t)3 * M0;
    float* ob     = big + (size_t)4 * M0;
    float* value  = big;
    float* tgt_a  = ws + (size_t)VSZ;
    float* query  = tgt_a + M0;
    float* offs   = query + M0;
    float* awb    = offs + M0;              // B*LQ*128
    float* sampled= awb + (size_t)Bv * LQv * 128;
    float* tgt_b  = sampled + M0;
    float* hidden = tgt_b + M0;             // B*LQ*DFF
    float* tmp    = hidden + (size_t)Bv * LQv * DFFv;

    const int Mq = Bv * LQv;                // 4096 rows
    dim3 blk256(256);

    // 1. qk = tgt + query_pos
    add_kernel<<<dim3(M0 / 4 / 256), blk256, 0, stream>>>(tgt, query_pos, qk, M0 / 4);

    // 2. q,k,v projections
    gemm_bias<<<dim3(Cv / BN, Mq / BM), blk256, 0, stream>>>(qk, in_w,                    in_b,       qb, Mq, Cv, Cv, 0);
    gemm_bias<<<dim3(Cv / BN, Mq / BM), blk256, 0, stream>>>(qk, in_w + (size_t)Cv * Cv,  in_b + Cv,  kb, Mq, Cv, Cv, 0);
    gemm_bias<<<dim3(Cv / BN, Mq / BM), blk256, 0, stream>>>(tgt, in_w + (size_t)2*Cv*Cv, in_b + 2*Cv, vb, Mq, Cv, Cv, 0);

    // 3. self-attention
    attn_kernel<<<dim3(LQv / 64, Hv, Bv), dim3(64), 0, stream>>>(qb, kb, vb, ob);

    // 4. output projection, 5. LN2 residual
    gemm_bias<<<dim3(Cv / BN, Mq / BM), blk256, 0, stream>>>(ob, sa_w, sa_b, tmp, Mq, Cv, Cv, 0);
    ln_residual<<<dim3(Mq), blk256, 0, stream>>>(tgt, tmp, ln2_g, ln2_b, tgt_a);

    // 6. query = tgt_a + query_pos
    add_kernel<<<dim3(M0 / 4 / 256), blk256, 0, stream>>>(tgt_a, query_pos, query, M0 / 4);

    // 7. value projection (the big GEMM)
    gemm_bias<<<dim3(Cv / BN, (Bv * LSRCv) / BM), blk256, 0, stream>>>(src, val_w, val_b, value, Bv * LSRCv, Cv, Cv, 0);

    // 8. offsets, 9. attention-weight logits
    gemm_bias<<<dim3(Cv / BN, Mq / BM), blk256, 0, stream>>>(query, off_w, off_b, offs, Mq, Cv, Cv, 0);
    gemm_bias<<<dim3(128 / BN, Mq / BM), blk256, 0, stream>>>(query, aw_w, aw_b, awb, Mq, 128, Cv, 0);

    // 10. deformable bilinear sampling
    deform_sample<<<dim3(Bv * LQv), blk256, 0, stream>>>(value, offs, awb, ref_pts, sampled);

    // 11. cross-attn output projection, 12. LN1 residual
    gemm_bias<<<dim3(Cv / BN, Mq / BM), blk256, 0, stream>>>(sampled, co_w, co_b, tmp, Mq, Cv, Cv, 0);
    ln_residual<<<dim3(Mq), blk256, 0, stream>>>(tgt_a, tmp, ln1_g, ln1_b, tgt_b);

    // 13./14. FFN, 15. LN3 → d_out
    gemm_bias<<<dim3(DFFv / BN, Mq / BM), blk256, 0, stream>>>(tgt_b, f1_w, f1_b, hidden, Mq, DFFv, Cv, 1);
    gemm_bias<<<dim3(Cv / BN, Mq / BM), blk256, 0, stream>>>(hidden, f2_w, f2_b, tmp, Mq, Cv, DFFv, 0);
    ln_residual<<<dim3(Mq), blk256, 0, stream>>>(tgt_b, tmp, ln3_g, ln3_b, (float*)d_out);
}

// Round 2
// 1007.381 us; speedup vs baseline: 1.0841x; 1.0841x over previous
//
#include <hip/hip_runtime.h>
#include <hip/hip_bf16.h>
#include <math.h>

// Problem constants
#define Bv   4
#define LQv  1024
#define Cv   256
#define Hv   8
#define Lv   4
#define Pv   4
#define DFFv 1024
#define DHv  32
#define LSRCv 21760   // 128*128 + 64*64 + 32*32 + 16*16

// ---------------------------------------------------------------------------
// elementwise add: out = a + b   (float4 vectorized)
__global__ __launch_bounds__(256) void add_kernel(const float* __restrict__ a,
                                                  const float* __restrict__ b,
                                                  float* __restrict__ out, int n4) {
    int i = blockIdx.x * blockDim.x + threadIdx.x;
    if (i < n4) {
        float4 av = ((const float4*)a)[i];
        float4 bv = ((const float4*)b)[i];
        float4 o;
        o.x = av.x + bv.x; o.y = av.y + bv.y; o.z = av.z + bv.z; o.w = av.w + bv.w;
        ((float4*)out)[i] = o;
    }
}

// ---------------------------------------------------------------------------
// C[M,N] = A[M,K] @ W[N,K]^T + bias[N], optional relu.
// Requires M%64==0, N%64==0, K%16==0 (true for all our shapes).
#define BM 64
#define BN 64
#define BKt 16
__global__ __launch_bounds__(256) void gemm_bias(const float* __restrict__ A,
                                                 const float* __restrict__ W,
                                                 const float* __restrict__ bias,
                                                 float* __restrict__ Cmat,
                                                 int M, int N, int K, int relu) {
    __shared__ float As[BKt][BM];
    __shared__ float Bs[BKt][BN];
    const int bm = blockIdx.y * BM;
    const int bn = blockIdx.x * BN;
    const int tid = threadIdx.x;
    const int tr = (tid >> 4) << 2;   // row offset 0..60
    const int tc = (tid & 15) << 2;   // col offset 0..60
    float acc[4][4] = {};

    const int lrow = tid >> 2;          // 0..63
    const int lc4  = (tid & 3) << 2;    // 0,4,8,12
    const float* Aptr = A + (size_t)(bm + lrow) * K + lc4;
    const float* Wptr = W + (size_t)(bn + lrow) * K + lc4;

    for (int k0 = 0; k0 < K; k0 += BKt) {
        float4 a4 = *(const float4*)(Aptr + k0);
        float4 w4 = *(const float4*)(Wptr + k0);
        As[lc4 + 0][lrow] = a4.x; As[lc4 + 1][lrow] = a4.y;
        As[lc4 + 2][lrow] = a4.z; As[lc4 + 3][lrow] = a4.w;
        Bs[lc4 + 0][lrow] = w4.x; Bs[lc4 + 1][lrow] = w4.y;
        Bs[lc4 + 2][lrow] = w4.z; Bs[lc4 + 3][lrow] = w4.w;
        __syncthreads();
#pragma unroll
        for (int kk = 0; kk < BKt; ++kk) {
            float a0 = As[kk][tr + 0], a1 = As[kk][tr + 1];
            float a2 = As[kk][tr + 2], a3 = As[kk][tr + 3];
            float b0 = Bs[kk][tc + 0], b1 = Bs[kk][tc + 1];
            float b2 = Bs[kk][tc + 2], b3 = Bs[kk][tc + 3];
            acc[0][0] = fmaf(a0, b0, acc[0][0]); acc[0][1] = fmaf(a0, b1, acc[0][1]);
            acc[0][2] = fmaf(a0, b2, acc[0][2]); acc[0][3] = fmaf(a0, b3, acc[0][3]);
            acc[1][0] = fmaf(a1, b0, acc[1][0]); acc[1][1] = fmaf(a1, b1, acc[1][1]);
            acc[1][2] = fmaf(a1, b2, acc[1][2]); acc[1][3] = fmaf(a1, b3, acc[1][3]);
            acc[2][0] = fmaf(a2, b0, acc[2][0]); acc[2][1] = fmaf(a2, b1, acc[2][1]);
            acc[2][2] = fmaf(a2, b2, acc[2][2]); acc[2][3] = fmaf(a2, b3, acc[2][3]);
            acc[3][0] = fmaf(a3, b0, acc[3][0]); acc[3][1] = fmaf(a3, b1, acc[3][1]);
            acc[3][2] = fmaf(a3, b2, acc[3][2]); acc[3][3] = fmaf(a3, b3, acc[3][3]);
        }
        __syncthreads();
    }
#pragma unroll
    for (int i = 0; i < 4; ++i) {
#pragma unroll
        for (int j = 0; j < 4; ++j) {
            float v = acc[i][j] + bias[bn + tc + j];
            if (relu) v = fmaxf(v, 0.f);
            Cmat[(size_t)(bm + tr + i) * N + bn + tc + j] = v;
        }
    }
}

// ---------------------------------------------------------------------------
// Flash-style self-attention, key-split across 4 waves.
// grid: (LQ/64, H, B), block: 256 (4 waves).
// Wave w handles keys [w*256, (w+1)*256) for the block's 64 queries
// (lane = query). K/V rows are lane-UNIFORM addresses -> scalar/broadcast
// loads, no LDS in the hot loop. Partial (m,l,acc) merged through LDS.
__global__ __launch_bounds__(256) void attn_kernel(const float* __restrict__ Q,
                                                   const float* __restrict__ Kb,
                                                   const float* __restrict__ Vb,
                                                   float* __restrict__ O) {
    const int b = blockIdx.z, h = blockIdx.y, qt = blockIdx.x;
    const int tid = threadIdx.x;
    const int wid = tid >> 6, lane = tid & 63;
    const int q = qt * 64 + lane;

    float qreg[32];
    const float* qrow = Q + ((size_t)(b * LQv + q)) * Cv + h * DHv;
#pragma unroll
    for (int d = 0; d < 32; ++d) qreg[d] = qrow[d];

    const float* kbase = Kb + ((size_t)(b * LQv)) * Cv + h * DHv;
    const float* vbase = Vb + ((size_t)(b * LQv)) * Cv + h * DHv;

    float mval = -1e30f, lsum = 0.f;
    float acc[32] = {};
    const float scale = 0.17677669529663687f;  // 1/sqrt(32)

#pragma unroll 1
    for (int c = 0; c < 16; ++c) {
        const int k0 = wid * 256 + c * 16;
        float s[16];
        float cmax = mval;
#pragma unroll
        for (int j = 0; j < 16; ++j) {
            const float* kr = kbase + (size_t)(k0 + j) * Cv;   // lane-uniform
            float dot = 0.f;
#pragma unroll
            for (int d = 0; d < 32; ++d) dot = fmaf(qreg[d], kr[d], dot);
            s[j] = dot * scale;
            cmax = fmaxf(cmax, s[j]);
        }
        float corr = __expf(mval - cmax);
        mval = cmax;
        lsum *= corr;
#pragma unroll
        for (int d = 0; d < 32; ++d) acc[d] *= corr;
#pragma unroll
        for (int j = 0; j < 16; ++j) {
            float p = __expf(s[j] - cmax);
            lsum += p;
            const float* vr = vbase + (size_t)(k0 + j) * Cv;   // lane-uniform
#pragma unroll
            for (int d = 0; d < 32; ++d) acc[d] = fmaf(p, vr[d], acc[d]);
        }
    }

    // merge the 4 per-wave partial states (pad row to 35 floats: stride 35
    // mod 32 = 3, coprime -> at most 2-way bank aliasing = free)
    __shared__ float red[4][64][35];
    red[wid][lane][0] = mval;
    red[wid][lane][1] = lsum;
#pragma unroll
    for (int d = 0; d < 32; ++d) red[wid][lane][2 + d] = acc[d];
    __syncthreads();
    if (wid == 0) {
        float m = red[0][lane][0];
#pragma unroll
        for (int w = 1; w < 4; ++w) m = fmaxf(m, red[w][lane][0]);
        float l = 0.f, o[32] = {};
#pragma unroll
        for (int w = 0; w < 4; ++w) {
            float cc = __expf(red[w][lane][0] - m);
            l += red[w][lane][1] * cc;
#pragma unroll
            for (int d = 0; d < 32; ++d) o[d] = fmaf(cc, red[w][lane][2 + d], o[d]);
        }
        float inv = 1.f / l;
        float* orow = O + ((size_t)(b * LQv + q)) * Cv + h * DHv;
#pragma unroll
        for (int d = 0; d < 32; ++d) orow[d] = o[d] * inv;
    }
}

// ---------------------------------------------------------------------------
// Deformable sampling. grid: B*LQ blocks, 256 threads: thread = (h, d).
__global__ __launch_bounds__(256) void deform_sample(const float* __restrict__ value,
                                                     const float* __restrict__ offs,
                                                     const float* __restrict__ awl,
                                                     const float* __restrict__ ref,
                                                     float* __restrict__ out) {
    const int bq = blockIdx.x;          // b*LQ + q
    const int b = bq >> 10;
    const int tid = threadIdx.x;
    const int h = tid >> 5, d = tid & 31;

    // softmax over the 16 (l,p) attention-weight logits of this head
    const float* aw = awl + (size_t)bq * (Hv * Lv * Pv) + h * 16;
    float w[16];
    float mx = -1e30f;
#pragma unroll
    for (int j = 0; j < 16; ++j) { w[j] = aw[j]; mx = fmaxf(mx, w[j]); }
    float ssum = 0.f;
#pragma unroll
    for (int j = 0; j < 16; ++j) { w[j] = __expf(w[j] - mx); ssum += w[j]; }
    float invs = 1.f / ssum;

    const float* op = offs + (size_t)bq * 256 + h * 32;   // (L,P,2) for this head
    const float* rp = ref + (size_t)bq * (Lv * 2);

    const int starts[4] = {0, 16384, 20480, 21504};
    const int WHl[4] = {128, 64, 32, 16};

    float acc = 0.f;
#pragma unroll 1
    for (int l = 0; l < 4; ++l) {
        const int wl = WHl[l];
        const float rx = rp[l * 2 + 0], ry = rp[l * 2 + 1];
        const float* vbase = value + ((size_t)b * LSRCv + starts[l]) * Cv + h * DHv + d;
#pragma unroll 1
        for (int p = 0; p < 4; ++p) {
            float ox = op[l * 8 + p * 2 + 0], oy = op[l * 8 + p * 2 + 1];
            // (ref + off/norm)*wl - 0.5 == ref*wl + off - 0.5  (square levels)
            float x = rx * (float)wl + ox - 0.5f;
            float y = ry * (float)wl + oy - 0.5f;
            float fx0 = floorf(x), fy0 = floorf(y);
            int x0 = (int)fx0, y0 = (int)fy0;
            float tx = x - fx0, ty = y - fy0;
            float w00 = (1.f - tx) * (1.f - ty);
            float w10 = tx * (1.f - ty);
            float w01 = (1.f - tx) * ty;
            float w11 = tx * ty;
            float s = 0.f;
            bool xin0 = (x0 >= 0) & (x0 < wl);
            bool xin1 = (x0 + 1 >= 0) & (x0 + 1 < wl);
            bool yin0 = (y0 >= 0) & (y0 < wl);
            bool yin1 = (y0 + 1 >= 0) & (y0 + 1 < wl);
            if (yin0) {
                if (xin0) s = fmaf(w00, vbase[(size_t)(y0 * wl + x0) * Cv], s);
                if (xin1) s = fmaf(w10, vbase[(size_t)(y0 * wl + x0 + 1) * Cv], s);
            }
            if (yin1) {
                if (xin0) s = fmaf(w01, vbase[(size_t)((y0 + 1) * wl + x0) * Cv], s);
                if (xin1) s = fmaf(w11, vbase[(size_t)((y0 + 1) * wl + x0 + 1) * Cv], s);
            }
            acc = fmaf(w[l * 4 + p] * invs, s, acc);
        }
    }
    out[(size_t)bq * Cv + h * DHv + d] = acc;
}

// ---------------------------------------------------------------------------
// out = LayerNorm(x + r) * g + b    one block per row of 256
__global__ __launch_bounds__(256) void ln_residual(const float* __restrict__ x,
                                                   const float* __restrict__ r,
                                                   const float* __restrict__ g,
                                                   const float* __restrict__ bta,
                                                   float* __restrict__ out) {
    const int row = blockIdx.x;
    const int tid = threadIdx.x;
    float v = x[(size_t)row * Cv + tid] + r[(size_t)row * Cv + tid];
    float s = v, sq = v * v;
#pragma unroll
    for (int off = 32; off > 0; off >>= 1) {
        s  += __shfl_down(s, off, 64);
        sq += __shfl_down(sq, off, 64);
    }
    __shared__ float ss[4], sqq[4];
    int wid = tid >> 6;
    if ((tid & 63) == 0) { ss[wid] = s; sqq[wid] = sq; }
    __syncthreads();
    __shared__ float meansh, rstdsh;
    if (tid == 0) {
        float S = ss[0] + ss[1] + ss[2] + ss[3];
        float Q = sqq[0] + sqq[1] + sqq[2] + sqq[3];
        float mean = S * (1.f / Cv);
        float var = Q * (1.f / Cv) - mean * mean;
        meansh = mean;
        rstdsh = rsqrtf(var + 1e-5f);
    }
    __syncthreads();
    out[(size_t)row * Cv + tid] = (v - meansh) * rstdsh * g[tid] + bta[tid];
}

// ---------------------------------------------------------------------------
extern "C" void kernel_launch(void* const* d_in, const int* in_sizes, int n_in,
                              void* d_out, int out_size, void* d_ws, size_t ws_size,
                              hipStream_t stream) {
    const float* tgt       = (const float*)d_in[0];
    const float* query_pos = (const float*)d_in[1];
    const float* ref_pts   = (const float*)d_in[2];
    const float* src       = (const float*)d_in[3];
    const float* in_w      = (const float*)d_in[4];
    const float* in_b      = (const float*)d_in[5];
    const float* sa_w      = (const float*)d_in[6];
    const float* sa_b      = (const float*)d_in[7];
    const float* off_w     = (const float*)d_in[8];
    const float* off_b     = (const float*)d_in[9];
    const float* aw_w      = (const float*)d_in[10];
    const float* aw_b      = (const float*)d_in[11];
    const float* val_w     = (const float*)d_in[12];
    const float* val_b     = (const float*)d_in[13];
    const float* co_w      = (const float*)d_in[14];
    const float* co_b      = (const float*)d_in[15];
    const float* ln1_g     = (const float*)d_in[16];
    const float* ln1_b     = (const float*)d_in[17];
    const float* ln2_g     = (const float*)d_in[18];
    const float* ln2_b     = (const float*)d_in[19];
    const float* ln3_g     = (const float*)d_in[20];
    const float* ln3_b     = (const float*)d_in[21];
    const float* f1_w      = (const float*)d_in[22];
    const float* f1_b      = (const float*)d_in[23];
    const float* f2_w      = (const float*)d_in[24];
    const float* f2_b      = (const float*)d_in[25];

    const int M0  = Bv * LQv * Cv;          // 1048576
    const int VSZ = Bv * LSRCv * Cv;        // 22282240
    float* ws = (float*)d_ws;

    // Phase-A buffers alias the (later) value region — lifetimes don't overlap.
    float* big    = ws;                     // VSZ floats
    float* qk     = big;
    float* qb     = big + (size_t)M0;
    float* kb     = big + (size_t)2 * M0;
    float* vb     = big + (size_t)3 * M0;
    float* ob     = big + (size_t)4 * M0;
    float* value  = big;
    float* tgt_a  = ws + (size_t)VSZ;
    float* query  = tgt_a + M0;
    float* offs   = query + M0;
    float* awb    = offs + M0;              // B*LQ*128
    float* sampled= awb + (size_t)Bv * LQv * 128;
    float* tgt_b  = sampled + M0;
    float* hidden = tgt_b + M0;             // B*LQ*DFF
    float* tmp    = hidden + (size_t)Bv * LQv * DFFv;

    const int Mq = Bv * LQv;                // 4096 rows
    dim3 blk256(256);

    // 1. qk = tgt + query_pos
    add_kernel<<<dim3(M0 / 4 / 256), blk256, 0, stream>>>(tgt, query_pos, qk, M0 / 4);

    // 2. q,k,v projections
    gemm_bias<<<dim3(Cv / BN, Mq / BM), blk256, 0, stream>>>(qk, in_w,                    in_b,       qb, Mq, Cv, Cv, 0);
    gemm_bias<<<dim3(Cv / BN, Mq / BM), blk256, 0, stream>>>(qk, in_w + (size_t)Cv * Cv,  in_b + Cv,  kb, Mq, Cv, Cv, 0);
    gemm_bias<<<dim3(Cv / BN, Mq / BM), blk256, 0, stream>>>(tgt, in_w + (size_t)2*Cv*Cv, in_b + 2*Cv, vb, Mq, Cv, Cv, 0);

    // 3. self-attention (4-wave key-split flash)
    attn_kernel<<<dim3(LQv / 64, Hv, Bv), blk256, 0, stream>>>(qb, kb, vb, ob);

    // 4. output projection, 5. LN2 residual
    gemm_bias<<<dim3(Cv / BN, Mq / BM), blk256, 0, stream>>>(ob, sa_w, sa_b, tmp, Mq, Cv, Cv, 0);
    ln_residual<<<dim3(Mq), blk256, 0, stream>>>(tgt, tmp, ln2_g, ln2_b, tgt_a);

    // 6. query = tgt_a + query_pos
    add_kernel<<<dim3(M0 / 4 / 256), blk256, 0, stream>>>(tgt_a, query_pos, query, M0 / 4);

    // 7. value projection (the big GEMM)
    gemm_bias<<<dim3(Cv / BN, (Bv * LSRCv) / BM), blk256, 0, stream>>>(src, val_w, val_b, value, Bv * LSRCv, Cv, Cv, 0);

    // 8. offsets, 9. attention-weight logits
    gemm_bias<<<dim3(Cv / BN, Mq / BM), blk256, 0, stream>>>(query, off_w, off_b, offs, Mq, Cv, Cv, 0);
    gemm_bias<<<dim3(128 / BN, Mq / BM), blk256, 0, stream>>>(query, aw_w, aw_b, awb, Mq, 128, Cv, 0);

    // 10. deformable bilinear sampling
    deform_sample<<<dim3(Bv * LQv), blk256, 0, stream>>>(value, offs, awb, ref_pts, sampled);

    // 11. cross-attn output projection, 12. LN1 residual
    gemm_bias<<<dim3(Cv / BN, Mq / BM), blk256, 0, stream>>>(sampled, co_w, co_b, tmp, Mq, Cv, Cv, 0);
    ln_residual<<<dim3(Mq), blk256, 0, stream>>>(tgt_a, tmp, ln1_g, ln1_b, tgt_b);

    // 13./14. FFN, 15. LN3 → d_out
    gemm_bias<<<dim3(DFFv / BN, Mq / BM), blk256, 0, stream>>>(tgt_b, f1_w, f1_b, hidden, Mq, DFFv, Cv, 1);
    gemm_bias<<<dim3(Cv / BN, Mq / BM), blk256, 0, stream>>>(hidden, f2_w, f2_b, tmp, Mq, Cv, DFFv, 0);
    ln_residual<<<dim3(Mq), blk256, 0, stream>>>(tgt_b, tmp, ln3_g, ln3_b, (float*)d_out);
}